// Round 1
// baseline (1165.146 us; speedup 1.0000x reference)
//
#include <hip/hip_runtime.h>

#define NN 384
#define DM 256
#define NH 4
#define DHD 64
#define FF 1024
#define HIDN 512
#define NCLS 56
#define NPAIR (NN*(NN-1))   // 147072

// ---------------- generic small GEMM: C[M,Nc] = A[M,K] @ B[K,Nc] + bias ----
template<int RELU>
__global__ __launch_bounds__(256)
void gemm_bias(const float* __restrict__ A, const float* __restrict__ B,
               const float* __restrict__ bias, float* __restrict__ C,
               int M, int K, int Nc) {
  int c0 = (blockIdx.x * 64 + threadIdx.x) * 4;
  int row = blockIdx.y * 4 + threadIdx.y;
  if (row >= M || c0 >= Nc) return;
  const float* __restrict__ a = A + row * K;
  float4 acc = make_float4(0.f, 0.f, 0.f, 0.f);
  for (int k = 0; k < K; ++k) {
    float av = a[k];
    float4 b = *reinterpret_cast<const float4*>(B + (size_t)k * Nc + c0);
    acc.x += av * b.x; acc.y += av * b.y; acc.z += av * b.z; acc.w += av * b.w;
  }
  float4 bb = *reinterpret_cast<const float4*>(bias + c0);
  acc.x += bb.x; acc.y += bb.y; acc.z += bb.z; acc.w += bb.w;
  if (RELU) {
    acc.x = fmaxf(acc.x, 0.f); acc.y = fmaxf(acc.y, 0.f);
    acc.z = fmaxf(acc.z, 0.f); acc.w = fmaxf(acc.w, 0.f);
  }
  *reinterpret_cast<float4*>(C + (size_t)row * Nc + c0) = acc;
}

// ---------------- attention scores: sc[h,n,m] = q[n,h,:]·k[m,h,:] * 0.125 --
__global__ __launch_bounds__(256)
void attn_scores(const float* __restrict__ qkv, float* __restrict__ sc) {
  __shared__ float kl[64][65];
  int h = blockIdx.z;
  int m0 = blockIdx.x * 64, n0 = blockIdx.y * 4;
  int tid = threadIdx.y * 64 + threadIdx.x;
  // stage K rows m0..m0+63 (64 dims) into LDS
  for (int t = tid; t < 64 * 16; t += 256) {
    int r = t >> 4, c4 = t & 15;
    float4 kv = *reinterpret_cast<const float4*>(qkv + (size_t)(m0 + r) * 768 + 256 + h * 64 + c4 * 4);
    kl[r][c4 * 4 + 0] = kv.x; kl[r][c4 * 4 + 1] = kv.y;
    kl[r][c4 * 4 + 2] = kv.z; kl[r][c4 * 4 + 3] = kv.w;
  }
  __syncthreads();
  int n = n0 + threadIdx.y, m = threadIdx.x;
  const float* __restrict__ q = qkv + (size_t)n * 768 + h * 64;
  float s = 0.f;
  #pragma unroll 8
  for (int d = 0; d < 64; ++d) s += q[d] * kl[m][d];
  sc[((size_t)h * NN + n) * NN + m0 + m] = s * 0.125f;
}

// ---------------- row softmax over 384 elements (block=128) ---------------
__global__ __launch_bounds__(128)
void softmax_rows(float* __restrict__ sc) {
  float* row = sc + (size_t)blockIdx.x * NN;
  int t = threadIdx.x;
  float v0 = row[t], v1 = row[t + 128], v2 = row[t + 256];
  __shared__ float red[128];
  float m = fmaxf(v0, fmaxf(v1, v2));
  red[t] = m; __syncthreads();
  for (int s = 64; s > 0; s >>= 1) { if (t < s) red[t] = fmaxf(red[t], red[t + s]); __syncthreads(); }
  m = red[0]; __syncthreads();
  float e0 = expf(v0 - m), e1 = expf(v1 - m), e2 = expf(v2 - m);
  red[t] = e0 + e1 + e2; __syncthreads();
  for (int s = 64; s > 0; s >>= 1) { if (t < s) red[t] += red[t + s]; __syncthreads(); }
  float inv = 1.0f / red[0];
  row[t] = e0 * inv; row[t + 128] = e1 * inv; row[t + 256] = e2 * inv;
}

// ---------------- PV: o[n, h*64+d] = sum_m attn[h,n,m] * v[m,h,d] ---------
__global__ __launch_bounds__(256)
void attn_pv(const float* __restrict__ qkv, const float* __restrict__ attn,
             float* __restrict__ o) {
  int d = threadIdx.x;
  int h = blockIdx.x;
  int n = blockIdx.y * 4 + threadIdx.y;
  const float* __restrict__ arow = attn + ((size_t)h * NN + n) * NN;
  const float* __restrict__ vcol = qkv + 512 + h * 64 + d;
  float acc = 0.f;
  for (int m = 0; m < NN; ++m) acc += arow[m] * vcol[(size_t)m * 768];
  o[(size_t)n * DM + h * 64 + d] = acc;
}

// ---------------- residual add + LayerNorm (block=256 = one row) ----------
__global__ __launch_bounds__(256)
void add_ln(float* __restrict__ x, const float* __restrict__ r,
            const float* __restrict__ g, const float* __restrict__ b) {
  int i = blockIdx.x, t = threadIdx.x;
  float v = x[(size_t)i * DM + t] + r[(size_t)i * DM + t];
  __shared__ float red[256];
  red[t] = v; __syncthreads();
  for (int s = 128; s > 0; s >>= 1) { if (t < s) red[t] += red[t + s]; __syncthreads(); }
  float mu = red[0] * (1.0f / DM); __syncthreads();
  float dv = v - mu;
  red[t] = dv * dv; __syncthreads();
  for (int s = 128; s > 0; s >>= 1) { if (t < s) red[t] += red[t + s]; __syncthreads(); }
  float var = red[0] * (1.0f / DM);
  float inv = rsqrtf(var + 1e-5f);
  x[(size_t)i * DM + t] = dv * inv * g[t] + b[t];
}

// ---------------- U/V for relation MLP layer-1 decomposition --------------
// U[i,k] = x[i,:]@W1[0:256,k]   + boxes[i,:]@W1[512:516,k] + b1[k]
// V[j,k] = x[j,:]@W1[256:512,k] + boxes[j,:]@W1[516:520,k]
__global__ __launch_bounds__(256)
void compute_uv(const float* __restrict__ x, const float* __restrict__ boxes,
                const float* __restrict__ w1, const float* __restrict__ b1,
                float* __restrict__ U, float* __restrict__ V) {
  int k = blockIdx.x * 256 + threadIdx.x;   // 0..511
  int i = blockIdx.y;
  const float* __restrict__ xr = x + (size_t)i * DM;
  float u = 0.f, v = 0.f;
  for (int d = 0; d < DM; ++d) {
    float xv = xr[d];
    u += xv * w1[(size_t)d * HIDN + k];
    v += xv * w1[(size_t)(DM + d) * HIDN + k];
  }
  const float* __restrict__ br = boxes + (size_t)i * 4;
  #pragma unroll
  for (int c = 0; c < 4; ++c) {
    float bv = br[c];
    u += bv * w1[(size_t)(512 + c) * HIDN + k];
    v += bv * w1[(size_t)(516 + c) * HIDN + k];
  }
  U[(size_t)i * HIDN + k] = u + b1[k];
  V[(size_t)i * HIDN + k] = v;
}

// ---------------- transpose V[384,512] -> VT[512,384] ---------------------
__global__ __launch_bounds__(256)
void transpose_v(const float* __restrict__ V, float* __restrict__ VT) {
  int idx = blockIdx.x * 256 + threadIdx.x;
  if (idx >= HIDN * NN) return;
  int k = idx / NN, j = idx % NN;
  VT[idx] = V[(size_t)j * HIDN + k];
}

// ---------------- pair MLP: logits(i,j) = relu(U[i]+V[j]) @ W2 + b2 -------
__global__ __launch_bounds__(64)
void pair_mlp(const float* __restrict__ U, const float* __restrict__ VT,
              const float* __restrict__ w2, const float* __restrict__ b2,
              float* __restrict__ out) {
  int i = blockIdx.y;
  int j = blockIdx.x * 64 + threadIdx.x;
  const float* __restrict__ u = U + (size_t)i * HIDN;
  float acc[NCLS];
  #pragma unroll
  for (int c = 0; c < NCLS; ++c) acc[c] = 0.f;
  for (int k = 0; k < HIDN; ++k) {
    float hv = fmaxf(u[k] + VT[(size_t)k * NN + j], 0.f);
    const float4* __restrict__ w2r = reinterpret_cast<const float4*>(w2 + (size_t)k * NCLS);
    #pragma unroll
    for (int c4 = 0; c4 < NCLS / 4; ++c4) {
      float4 w = w2r[c4];
      acc[c4 * 4 + 0] += hv * w.x;
      acc[c4 * 4 + 1] += hv * w.y;
      acc[c4 * 4 + 2] += hv * w.z;
      acc[c4 * 4 + 3] += hv * w.w;
    }
  }
  if (j != i) {
    int p = i * (NN - 1) + (j > i ? j - 1 : j);
    out[2 * p + 0] = (float)i;
    out[2 * p + 1] = (float)j;
    float* __restrict__ lrow = out + 2 * (size_t)NPAIR + (size_t)p * NCLS;
    #pragma unroll
    for (int c = 0; c < NCLS; ++c) lrow[c] = acc[c] + b2[c];
  }
}

// --------------------------------------------------------------------------
extern "C" void kernel_launch(void* const* d_in, const int* in_sizes, int n_in,
                              void* d_out, int out_size, void* d_ws, size_t ws_size,
                              hipStream_t stream) {
  const float* node   = (const float*)d_in[0];   // [384,256]
  const float* boxes  = (const float*)d_in[1];   // [384,4]
  const float* w_in   = (const float*)d_in[2];   // [2,256,768]
  const float* b_in   = (const float*)d_in[3];   // [2,768]
  const float* w_out  = (const float*)d_in[4];   // [2,256,256]
  const float* b_out  = (const float*)d_in[5];   // [2,256]
  const float* fw1    = (const float*)d_in[6];   // [2,256,1024]
  const float* fb1    = (const float*)d_in[7];   // [2,1024]
  const float* fw2    = (const float*)d_in[8];   // [2,1024,256]
  const float* fb2    = (const float*)d_in[9];   // [2,256]
  const float* ln1g   = (const float*)d_in[10];  // [2,256]
  const float* ln1b   = (const float*)d_in[11];
  const float* ln2g   = (const float*)d_in[12];
  const float* ln2b   = (const float*)d_in[13];
  const float* mw1    = (const float*)d_in[14];  // [520,512]
  const float* mb1    = (const float*)d_in[15];  // [512]
  const float* mw2    = (const float*)d_in[16];  // [512,56]
  const float* mb2    = (const float*)d_in[17];  // [56]
  float* out = (float*)d_out;

  float* ws = (float*)d_ws;
  float* xbuf  = ws;                   // 384*256   = 98304
  float* qkv   = xbuf  + 98304;        // 384*768   = 294912
  float* sc    = qkv   + 294912;       // 4*384*384 = 589824
  float* attno = sc    + 589824;       // 384*256
  float* proj  = attno + 98304;        // 384*256
  float* ffh   = proj  + 98304;        // 384*1024  = 393216
  float* U     = ffh   + 393216;       // 384*512   = 196608
  float* V     = U     + 196608;       // 384*512
  float* VT    = V     + 196608;       // 512*384

  hipMemcpyAsync(xbuf, node, (size_t)NN * DM * sizeof(float),
                 hipMemcpyDeviceToDevice, stream);

  for (int l = 0; l < 2; ++l) {
    const float* wi  = w_in  + (size_t)l * DM * 768;
    const float* bi  = b_in  + (size_t)l * 768;
    const float* wo  = w_out + (size_t)l * DM * DM;
    const float* bo  = b_out + (size_t)l * DM;
    const float* w1l = fw1   + (size_t)l * DM * FF;
    const float* b1l = fb1   + (size_t)l * FF;
    const float* w2l = fw2   + (size_t)l * FF * DM;
    const float* b2l = fb2   + (size_t)l * DM;

    // QKV projection
    gemm_bias<0><<<dim3(3, 96), dim3(64, 4), 0, stream>>>(xbuf, wi, bi, qkv, NN, DM, 768);
    // scores
    attn_scores<<<dim3(6, 96, 4), dim3(64, 4), 0, stream>>>(qkv, sc);
    // softmax
    softmax_rows<<<dim3(NH * NN), dim3(128), 0, stream>>>(sc);
    // PV
    attn_pv<<<dim3(NH, 96), dim3(64, 4), 0, stream>>>(qkv, sc, attno);
    // output projection
    gemm_bias<0><<<dim3(1, 96), dim3(64, 4), 0, stream>>>(attno, wo, bo, proj, NN, DM, DM);
    // x = LN(x + proj)
    add_ln<<<dim3(NN), dim3(256), 0, stream>>>(xbuf, proj, ln1g + (size_t)l * DM, ln1b + (size_t)l * DM);
    // FFN
    gemm_bias<1><<<dim3(4, 96), dim3(64, 4), 0, stream>>>(xbuf, w1l, b1l, ffh, NN, DM, FF);
    gemm_bias<0><<<dim3(1, 96), dim3(64, 4), 0, stream>>>(ffh, w2l, b2l, proj, NN, FF, DM);
    // x = LN(x + ffn)
    add_ln<<<dim3(NN), dim3(256), 0, stream>>>(xbuf, proj, ln2g + (size_t)l * DM, ln2b + (size_t)l * DM);
  }

  // relation MLP layer-1 decomposition
  compute_uv<<<dim3(2, NN), dim3(256), 0, stream>>>(xbuf, boxes, mw1, mb1, U, V);
  transpose_v<<<dim3((HIDN * NN + 255) / 256), dim3(256), 0, stream>>>(V, VT);
  // pair kernel: one wave per (i, 64 j's)
  pair_mlp<<<dim3(6, NN), dim3(64), 0, stream>>>(U, VT, mw2, mb2, out);
}

// Round 2
// 461.067 us; speedup vs baseline: 2.5271x; 2.5271x over previous
//
#include <hip/hip_runtime.h>

#define NN 384
#define DM 256
#define NH 4
#define FF 1024
#define HIDN 512
#define NCLS 56
#define NPAIR (NN*(NN-1))   // 147072

// ---------------- tiled f32 GEMM: C = alpha*(A@B) + bias, optional relu ----
// 64x64 tile, 256 threads, each thread 4x4 outputs. K multiple of 16,
// M,N multiples of 64. Batched via blockIdx.z strides (element offsets).
__global__ __launch_bounds__(256)
void gemm_tile(const float* __restrict__ A, int lda, long sA,
               const float* __restrict__ B, int ldb, long sB,
               const float* __restrict__ bias,
               float* __restrict__ C, int ldc, long sC,
               int K, float alpha, int relu) {
  __shared__ float As[16][64];
  __shared__ float Bs[16][64];
  A += (size_t)blockIdx.z * sA;
  B += (size_t)blockIdx.z * sB;
  C += (size_t)blockIdx.z * sC;
  int tid = threadIdx.x;
  int tx = tid & 15;         // N direction (4 cols each)
  int ty = tid >> 4;         // M direction (4 rows each)
  int m0 = blockIdx.y * 64;
  int n0 = blockIdx.x * 64;
  int la_r = tid >> 2;          // 0..63 : row within A tile
  int la_k = (tid & 3) * 4;     // 0,4,8,12 : k offset
  int lb_k = tid >> 4;          // 0..15 : k within B tile
  int lb_n = (tid & 15) * 4;    // col offset

  float acc[4][4] = {};
  float4 av = *reinterpret_cast<const float4*>(A + (size_t)(m0 + la_r) * lda + la_k);
  float4 bv = *reinterpret_cast<const float4*>(B + (size_t)lb_k * ldb + n0 + lb_n);
  int nchunk = K >> 4;
  for (int ch = 0; ch < nchunk; ++ch) {
    __syncthreads();
    As[la_k + 0][la_r] = av.x;
    As[la_k + 1][la_r] = av.y;
    As[la_k + 2][la_r] = av.z;
    As[la_k + 3][la_r] = av.w;
    *reinterpret_cast<float4*>(&Bs[lb_k][lb_n]) = bv;
    if (ch + 1 < nchunk) {
      int k0 = (ch + 1) << 4;
      av = *reinterpret_cast<const float4*>(A + (size_t)(m0 + la_r) * lda + k0 + la_k);
      bv = *reinterpret_cast<const float4*>(B + (size_t)(k0 + lb_k) * ldb + n0 + lb_n);
    }
    __syncthreads();
    #pragma unroll
    for (int k = 0; k < 16; ++k) {
      float4 a4 = *reinterpret_cast<const float4*>(&As[k][ty * 4]);
      float4 b4 = *reinterpret_cast<const float4*>(&Bs[k][tx * 4]);
      acc[0][0] += a4.x * b4.x; acc[0][1] += a4.x * b4.y; acc[0][2] += a4.x * b4.z; acc[0][3] += a4.x * b4.w;
      acc[1][0] += a4.y * b4.x; acc[1][1] += a4.y * b4.y; acc[1][2] += a4.y * b4.z; acc[1][3] += a4.y * b4.w;
      acc[2][0] += a4.z * b4.x; acc[2][1] += a4.z * b4.y; acc[2][2] += a4.z * b4.z; acc[2][3] += a4.z * b4.w;
      acc[3][0] += a4.w * b4.x; acc[3][1] += a4.w * b4.y; acc[3][2] += a4.w * b4.z; acc[3][3] += a4.w * b4.w;
    }
  }
  float4 bb = make_float4(0.f, 0.f, 0.f, 0.f);
  if (bias) bb = *reinterpret_cast<const float4*>(bias + n0 + tx * 4);
  #pragma unroll
  for (int i = 0; i < 4; ++i) {
    float4 r;
    r.x = acc[i][0] * alpha + bb.x;
    r.y = acc[i][1] * alpha + bb.y;
    r.z = acc[i][2] * alpha + bb.z;
    r.w = acc[i][3] * alpha + bb.w;
    if (relu) {
      r.x = fmaxf(r.x, 0.f); r.y = fmaxf(r.y, 0.f);
      r.z = fmaxf(r.z, 0.f); r.w = fmaxf(r.w, 0.f);
    }
    *reinterpret_cast<float4*>(C + (size_t)(m0 + ty * 4 + i) * ldc + n0 + tx * 4) = r;
  }
}

// ---------------- transpose K heads: kt[h][d][m] = qkv[m][256+h*64+d] -----
__global__ __launch_bounds__(256)
void transpose_k(const float* __restrict__ qkv, float* __restrict__ kt) {
  int idx = blockIdx.x * 256 + threadIdx.x;   // NH*64*NN = 98304
  int m = idx % NN;
  int d = (idx / NN) & 63;
  int h = idx / (NN * 64);
  kt[idx] = qkv[(size_t)m * 768 + 256 + h * 64 + d];
}

// ---------------- row softmax over 384 elements (block=128) ---------------
__global__ __launch_bounds__(128)
void softmax_rows(float* __restrict__ sc) {
  float* row = sc + (size_t)blockIdx.x * NN;
  int t = threadIdx.x;
  float v0 = row[t], v1 = row[t + 128], v2 = row[t + 256];
  __shared__ float red[128];
  float m = fmaxf(v0, fmaxf(v1, v2));
  red[t] = m; __syncthreads();
  for (int s = 64; s > 0; s >>= 1) { if (t < s) red[t] = fmaxf(red[t], red[t + s]); __syncthreads(); }
  m = red[0]; __syncthreads();
  float e0 = expf(v0 - m), e1 = expf(v1 - m), e2 = expf(v2 - m);
  red[t] = e0 + e1 + e2; __syncthreads();
  for (int s = 64; s > 0; s >>= 1) { if (t < s) red[t] += red[t + s]; __syncthreads(); }
  float inv = 1.0f / red[0];
  row[t] = e0 * inv; row[t + 128] = e1 * inv; row[t + 256] = e2 * inv;
}

// ---------------- residual add + LayerNorm (block=256 = one row) ----------
__global__ __launch_bounds__(256)
void add_ln(float* __restrict__ x, const float* __restrict__ r,
            const float* __restrict__ g, const float* __restrict__ b) {
  int i = blockIdx.x, t = threadIdx.x;
  float v = x[(size_t)i * DM + t] + r[(size_t)i * DM + t];
  __shared__ float red[256];
  red[t] = v; __syncthreads();
  for (int s = 128; s > 0; s >>= 1) { if (t < s) red[t] += red[t + s]; __syncthreads(); }
  float mu = red[0] * (1.0f / DM); __syncthreads();
  float dv = v - mu;
  red[t] = dv * dv; __syncthreads();
  for (int s = 128; s > 0; s >>= 1) { if (t < s) red[t] += red[t + s]; __syncthreads(); }
  float var = red[0] * (1.0f / DM);
  float inv = rsqrtf(var + 1e-5f);
  x[(size_t)i * DM + t] = dv * inv * g[t] + b[t];
}

// ---------------- add box terms to U; build VT with box terms -------------
__global__ __launch_bounds__(256)
void uv_fixup(const float* __restrict__ boxes, const float* __restrict__ w1,
              float* __restrict__ U, const float* __restrict__ V,
              float* __restrict__ VT) {
  int idx = blockIdx.x * 256 + threadIdx.x;   // NN*HIDN
  int i = idx >> 9, k = idx & 511;
  float u = U[idx], v = V[idx];
  #pragma unroll
  for (int c = 0; c < 4; ++c) {
    float bv = boxes[i * 4 + c];
    u += bv * w1[(size_t)(512 + c) * HIDN + k];
    v += bv * w1[(size_t)(516 + c) * HIDN + k];
  }
  U[idx] = u;
  VT[(size_t)k * NN + i] = v;
}

// ---------------- pair MLP: logits(i,j) = relu(U[i]+V[j]) @ W2 + b2 -------
__global__ __launch_bounds__(64)
void pair_mlp(const float* __restrict__ U, const float* __restrict__ VT,
              const float* __restrict__ w2, const float* __restrict__ b2,
              float* __restrict__ out) {
  int i = blockIdx.y;
  int j = blockIdx.x * 64 + threadIdx.x;
  const float* __restrict__ u = U + (size_t)i * HIDN;
  float acc[NCLS];
  #pragma unroll
  for (int c = 0; c < NCLS; ++c) acc[c] = 0.f;
  for (int k = 0; k < HIDN; ++k) {
    float hv = fmaxf(u[k] + VT[(size_t)k * NN + j], 0.f);
    const float4* __restrict__ w2r = reinterpret_cast<const float4*>(w2 + (size_t)k * NCLS);
    #pragma unroll
    for (int c4 = 0; c4 < NCLS / 4; ++c4) {
      float4 w = w2r[c4];
      acc[c4 * 4 + 0] += hv * w.x;
      acc[c4 * 4 + 1] += hv * w.y;
      acc[c4 * 4 + 2] += hv * w.z;
      acc[c4 * 4 + 3] += hv * w.w;
    }
  }
  if (j != i) {
    int p = i * (NN - 1) + (j > i ? j - 1 : j);
    out[2 * p + 0] = (float)i;
    out[2 * p + 1] = (float)j;
    float* __restrict__ lrow = out + 2 * (size_t)NPAIR + (size_t)p * NCLS;
    #pragma unroll
    for (int c = 0; c < NCLS; ++c) lrow[c] = acc[c] + b2[c];
  }
}

// --------------------------------------------------------------------------
extern "C" void kernel_launch(void* const* d_in, const int* in_sizes, int n_in,
                              void* d_out, int out_size, void* d_ws, size_t ws_size,
                              hipStream_t stream) {
  const float* node   = (const float*)d_in[0];
  const float* boxes  = (const float*)d_in[1];
  const float* w_in   = (const float*)d_in[2];
  const float* b_in   = (const float*)d_in[3];
  const float* w_out  = (const float*)d_in[4];
  const float* b_out  = (const float*)d_in[5];
  const float* fw1    = (const float*)d_in[6];
  const float* fb1    = (const float*)d_in[7];
  const float* fw2    = (const float*)d_in[8];
  const float* fb2    = (const float*)d_in[9];
  const float* ln1g   = (const float*)d_in[10];
  const float* ln1b   = (const float*)d_in[11];
  const float* ln2g   = (const float*)d_in[12];
  const float* ln2b   = (const float*)d_in[13];
  const float* mw1    = (const float*)d_in[14];
  const float* mb1    = (const float*)d_in[15];
  const float* mw2    = (const float*)d_in[16];
  const float* mb2    = (const float*)d_in[17];
  float* out = (float*)d_out;

  float* ws = (float*)d_ws;
  float* xbuf  = ws;                   // 384*256
  float* qkv   = xbuf  + 98304;        // 384*768
  float* sc    = qkv   + 294912;       // 4*384*384
  float* attno = sc    + 589824;       // 384*256
  float* proj  = attno + 98304;        // 384*256
  float* ffh   = proj  + 98304;        // 384*1024
  float* U     = ffh   + 393216;       // 384*512
  float* V     = U     + 196608;       // 384*512
  float* VT    = V     + 196608;       // 512*384
  float* kt    = VT    + 196608;       // 4*64*384

  hipMemcpyAsync(xbuf, node, (size_t)NN * DM * sizeof(float),
                 hipMemcpyDeviceToDevice, stream);

  for (int l = 0; l < 2; ++l) {
    const float* wi  = w_in  + (size_t)l * DM * 768;
    const float* bi  = b_in  + (size_t)l * 768;
    const float* wo  = w_out + (size_t)l * DM * DM;
    const float* bo  = b_out + (size_t)l * DM;
    const float* w1l = fw1   + (size_t)l * DM * FF;
    const float* b1l = fb1   + (size_t)l * FF;
    const float* w2l = fw2   + (size_t)l * FF * DM;
    const float* b2l = fb2   + (size_t)l * DM;

    // QKV: [384,256]@[256,768]+bi
    gemm_tile<<<dim3(12, 6, 1), 256, 0, stream>>>(xbuf, DM, 0, wi, 768, 0, bi,
                                                  qkv, 768, 0, DM, 1.f, 0);
    // K transpose per head
    transpose_k<<<dim3(384), 256, 0, stream>>>(qkv, kt);
    // scores[h] = 0.125 * Q[h] @ KT[h]   (batched over h)
    gemm_tile<<<dim3(6, 6, NH), 256, 0, stream>>>(qkv, 768, 64, kt, NN, 64 * NN,
                                                  nullptr, sc, NN, (long)NN * NN,
                                                  64, 0.125f, 0);
    softmax_rows<<<dim3(NH * NN), 128, 0, stream>>>(sc);
    // attno[h] = attn[h] @ V[h]
    gemm_tile<<<dim3(1, 6, NH), 256, 0, stream>>>(sc, NN, (long)NN * NN,
                                                  qkv + 512, 768, 64, nullptr,
                                                  attno, DM, 64, NN, 1.f, 0);
    // proj = attno @ wo + bo
    gemm_tile<<<dim3(4, 6, 1), 256, 0, stream>>>(attno, DM, 0, wo, DM, 0, bo,
                                                 proj, DM, 0, DM, 1.f, 0);
    add_ln<<<dim3(NN), 256, 0, stream>>>(xbuf, proj, ln1g + (size_t)l * DM, ln1b + (size_t)l * DM);
    // FFN1 (relu)
    gemm_tile<<<dim3(16, 6, 1), 256, 0, stream>>>(xbuf, DM, 0, w1l, FF, 0, b1l,
                                                  ffh, FF, 0, DM, 1.f, 1);
    // FFN2
    gemm_tile<<<dim3(4, 6, 1), 256, 0, stream>>>(ffh, FF, 0, w2l, DM, 0, b2l,
                                                 proj, DM, 0, FF, 1.f, 0);
    add_ln<<<dim3(NN), 256, 0, stream>>>(xbuf, proj, ln2g + (size_t)l * DM, ln2b + (size_t)l * DM);
  }

  // relation MLP layer-1 decomposition: U = x@W1[0:256]+b1, V = x@W1[256:512]
  gemm_tile<<<dim3(8, 6, 1), 256, 0, stream>>>(xbuf, DM, 0, mw1, HIDN, 0, mb1,
                                               U, HIDN, 0, DM, 1.f, 0);
  gemm_tile<<<dim3(8, 6, 1), 256, 0, stream>>>(xbuf, DM, 0, mw1 + (size_t)DM * HIDN,
                                               HIDN, 0, nullptr, V, HIDN, 0, DM, 1.f, 0);
  uv_fixup<<<dim3(NN * HIDN / 256), 256, 0, stream>>>(boxes, mw1, U, V, VT);
  pair_mlp<<<dim3(6, NN), 64, 0, stream>>>(U, VT, mw2, mb2, out);
}

// Round 3
// 373.878 us; speedup vs baseline: 3.1164x; 1.2332x over previous
//
#include <hip/hip_runtime.h>

#define NN 384
#define DM 256
#define NH 4
#define FF 1024
#define HIDN 512
#define NCLS 56
#define NPAIR (NN*(NN-1))   // 147072

typedef __attribute__((ext_vector_type(8))) short short8v;
typedef __attribute__((ext_vector_type(4))) float f32x4;
typedef __attribute__((ext_vector_type(8))) unsigned short ushort8;

static __device__ __forceinline__ unsigned short f2bf(float f) {
  unsigned u = __float_as_uint(f);
  unsigned r = u + 0x7fff + ((u >> 16) & 1);   // RNE
  return (unsigned short)(r >> 16);
}

// ---------------- tiled f32 GEMM: C = alpha*(A@B) + bias, optional relu ----
__global__ __launch_bounds__(256)
void gemm_tile(const float* __restrict__ A, int lda, long sA,
               const float* __restrict__ B, int ldb, long sB,
               const float* __restrict__ bias,
               float* __restrict__ C, int ldc, long sC,
               int K, float alpha, int relu) {
  __shared__ float As[16][64];
  __shared__ float Bs[16][64];
  A += (size_t)blockIdx.z * sA;
  B += (size_t)blockIdx.z * sB;
  C += (size_t)blockIdx.z * sC;
  int tid = threadIdx.x;
  int tx = tid & 15;
  int ty = tid >> 4;
  int m0 = blockIdx.y * 64;
  int n0 = blockIdx.x * 64;
  int la_r = tid >> 2;
  int la_k = (tid & 3) * 4;
  int lb_k = tid >> 4;
  int lb_n = (tid & 15) * 4;

  float acc[4][4] = {};
  float4 av = *reinterpret_cast<const float4*>(A + (size_t)(m0 + la_r) * lda + la_k);
  float4 bv = *reinterpret_cast<const float4*>(B + (size_t)lb_k * ldb + n0 + lb_n);
  int nchunk = K >> 4;
  for (int ch = 0; ch < nchunk; ++ch) {
    __syncthreads();
    As[la_k + 0][la_r] = av.x;
    As[la_k + 1][la_r] = av.y;
    As[la_k + 2][la_r] = av.z;
    As[la_k + 3][la_r] = av.w;
    *reinterpret_cast<float4*>(&Bs[lb_k][lb_n]) = bv;
    if (ch + 1 < nchunk) {
      int k0 = (ch + 1) << 4;
      av = *reinterpret_cast<const float4*>(A + (size_t)(m0 + la_r) * lda + k0 + la_k);
      bv = *reinterpret_cast<const float4*>(B + (size_t)(k0 + lb_k) * ldb + n0 + lb_n);
    }
    __syncthreads();
    #pragma unroll
    for (int k = 0; k < 16; ++k) {
      float4 a4 = *reinterpret_cast<const float4*>(&As[k][ty * 4]);
      float4 b4 = *reinterpret_cast<const float4*>(&Bs[k][tx * 4]);
      acc[0][0] += a4.x * b4.x; acc[0][1] += a4.x * b4.y; acc[0][2] += a4.x * b4.z; acc[0][3] += a4.x * b4.w;
      acc[1][0] += a4.y * b4.x; acc[1][1] += a4.y * b4.y; acc[1][2] += a4.y * b4.z; acc[1][3] += a4.y * b4.w;
      acc[2][0] += a4.z * b4.x; acc[2][1] += a4.z * b4.y; acc[2][2] += a4.z * b4.z; acc[2][3] += a4.z * b4.w;
      acc[3][0] += a4.w * b4.x; acc[3][1] += a4.w * b4.y; acc[3][2] += a4.w * b4.z; acc[3][3] += a4.w * b4.w;
    }
  }
  float4 bb = make_float4(0.f, 0.f, 0.f, 0.f);
  if (bias) bb = *reinterpret_cast<const float4*>(bias + n0 + tx * 4);
  #pragma unroll
  for (int i = 0; i < 4; ++i) {
    float4 r;
    r.x = acc[i][0] * alpha + bb.x;
    r.y = acc[i][1] * alpha + bb.y;
    r.z = acc[i][2] * alpha + bb.z;
    r.w = acc[i][3] * alpha + bb.w;
    if (relu) {
      r.x = fmaxf(r.x, 0.f); r.y = fmaxf(r.y, 0.f);
      r.z = fmaxf(r.z, 0.f); r.w = fmaxf(r.w, 0.f);
    }
    *reinterpret_cast<float4*>(C + (size_t)(m0 + ty * 4 + i) * ldc + n0 + tx * 4) = r;
  }
}

// ---------------- transpose K heads ---------------------------------------
__global__ __launch_bounds__(256)
void transpose_k(const float* __restrict__ qkv, float* __restrict__ kt) {
  int idx = blockIdx.x * 256 + threadIdx.x;
  int m = idx % NN;
  int d = (idx / NN) & 63;
  int h = idx / (NN * 64);
  kt[idx] = qkv[(size_t)m * 768 + 256 + h * 64 + d];
}

// ---------------- row softmax over 384 ------------------------------------
__global__ __launch_bounds__(128)
void softmax_rows(float* __restrict__ sc) {
  float* row = sc + (size_t)blockIdx.x * NN;
  int t = threadIdx.x;
  float v0 = row[t], v1 = row[t + 128], v2 = row[t + 256];
  __shared__ float red[128];
  float m = fmaxf(v0, fmaxf(v1, v2));
  red[t] = m; __syncthreads();
  for (int s = 64; s > 0; s >>= 1) { if (t < s) red[t] = fmaxf(red[t], red[t + s]); __syncthreads(); }
  m = red[0]; __syncthreads();
  float e0 = expf(v0 - m), e1 = expf(v1 - m), e2 = expf(v2 - m);
  red[t] = e0 + e1 + e2; __syncthreads();
  for (int s = 64; s > 0; s >>= 1) { if (t < s) red[t] += red[t + s]; __syncthreads(); }
  float inv = 1.0f / red[0];
  row[t] = e0 * inv; row[t + 128] = e1 * inv; row[t + 256] = e2 * inv;
}

// ---------------- residual add + LayerNorm --------------------------------
__global__ __launch_bounds__(256)
void add_ln(float* __restrict__ x, const float* __restrict__ r,
            const float* __restrict__ g, const float* __restrict__ b) {
  int i = blockIdx.x, t = threadIdx.x;
  float v = x[(size_t)i * DM + t] + r[(size_t)i * DM + t];
  __shared__ float red[256];
  red[t] = v; __syncthreads();
  for (int s = 128; s > 0; s >>= 1) { if (t < s) red[t] += red[t + s]; __syncthreads(); }
  float mu = red[0] * (1.0f / DM); __syncthreads();
  float dv = v - mu;
  red[t] = dv * dv; __syncthreads();
  for (int s = 128; s > 0; s >>= 1) { if (t < s) red[t] += red[t + s]; __syncthreads(); }
  float var = red[0] * (1.0f / DM);
  float inv = rsqrtf(var + 1e-5f);
  x[(size_t)i * DM + t] = dv * inv * g[t] + b[t];
}

// ---------------- add box terms to U and V in place -----------------------
__global__ __launch_bounds__(256)
void uv_fixup(const float* __restrict__ boxes, const float* __restrict__ w1,
              float* __restrict__ U, float* __restrict__ V) {
  int idx = blockIdx.x * 256 + threadIdx.x;   // NN*HIDN
  int i = idx >> 9, k = idx & 511;
  float u = U[idx], v = V[idx];
  #pragma unroll
  for (int c = 0; c < 4; ++c) {
    float bv = boxes[i * 4 + c];
    u += bv * w1[(size_t)(512 + c) * HIDN + k];
    v += bv * w1[(size_t)(516 + c) * HIDN + k];
  }
  U[idx] = u;
  V[idx] = v;
}

// ---------------- pack W2 into MFMA B-fragment order (bf16) ---------------
// B-frag for 16x16x32: lane l holds B[k = ks*32 + (l>>4)*8 + r][n = nt*16 + (l&15)]
// layout: frag[((ks*4 + nt)*64 + l)*8 + r]
__global__ __launch_bounds__(256)
void prep_w2frag(const float* __restrict__ w2, unsigned short* __restrict__ frag) {
  int idx = blockIdx.x * 256 + threadIdx.x;   // 16*4*64 = 4096
  int l = idx & 63;
  int nt = (idx >> 6) & 3;
  int ks = idx >> 8;
  int kb = ks * 32 + ((l >> 4) * 8);
  int n = nt * 16 + (l & 15);
  #pragma unroll
  for (int r = 0; r < 8; ++r) {
    float v = (n < NCLS) ? w2[(size_t)(kb + r) * NCLS + n] : 0.f;
    frag[(size_t)idx * 8 + r] = f2bf(v);
  }
}

// ---------------- pair indices output -------------------------------------
__global__ __launch_bounds__(256)
void pair_idx_kernel(float* __restrict__ out) {
  int p = blockIdx.x * 256 + threadIdx.x;
  if (p >= NPAIR) return;
  int i = p / (NN - 1);
  int r = p - i * (NN - 1);
  int j = r + (r >= i ? 1 : 0);
  out[2 * p + 0] = (float)i;
  out[2 * p + 1] = (float)j;
}

// ---------------- pair MLP via MFMA ---------------------------------------
// Block: 256 thr = 4 waves. i-tile of 4 (blockIdx.y), j-tile of 64 (blockIdx.x).
// Wave w owns N-tile w (classes w*16..w*16+15). K=512 in 4 chunks of 128.
// LDS: hA[64 j][128 k] bf16, XOR-swizzled per 16B unit.
__global__ __launch_bounds__(256)
void pair_mfma(const float* __restrict__ U, const float* __restrict__ V,
               const unsigned short* __restrict__ w2frag,
               const float* __restrict__ b2, float* __restrict__ out) {
  __shared__ float4 hA_buf[64 * 16];   // 16KB, 16B-aligned
  char* hA = (char*)hA_buf;
  int j0 = blockIdx.x * 64;
  int i0 = blockIdx.y * 4;
  int tid = threadIdx.x;
  int wave = tid >> 6;        // = nt
  int lane = tid & 63;

  // B fragments for all 16 k-steps of this wave's n-tile (64 VGPRs)
  short8v bfrag[16];
  #pragma unroll
  for (int ks = 0; ks < 16; ++ks)
    bfrag[ks] = *reinterpret_cast<const short8v*>(
        w2frag + ((size_t)(ks * 4 + wave) * 64 + lane) * 8);

  int cls = wave * 16 + (lane & 15);
  float b2v = (cls < NCLS) ? b2[cls] : 0.f;

  int cj = tid >> 2;          // construction row 0..63
  int ks4 = tid & 3;          // construction k-seg 0..3 (32 floats each)
  const float* vrow = V + (size_t)(j0 + cj) * HIDN + ks4 * 32;

  for (int ii = 0; ii < 4; ++ii) {
    int i = i0 + ii;
    f32x4 acc[4] = {};
    const float* urow = U + (size_t)i * HIDN + ks4 * 32;
    #pragma unroll
    for (int ch = 0; ch < 4; ++ch) {
      __syncthreads();   // previous readers done
      // ---- construct hA chunk: h = relu(u + v) -> bf16, swizzled ----
      {
        const float4* v4 = reinterpret_cast<const float4*>(vrow + ch * 128);
        const float4* u4 = reinterpret_cast<const float4*>(urow + ch * 128);
        #pragma unroll
        for (int w = 0; w < 4; ++w) {
          float4 va = v4[w * 2], vb = v4[w * 2 + 1];
          float4 ua = u4[w * 2], ub = u4[w * 2 + 1];
          ushort8 hv;
          hv[0] = f2bf(fmaxf(va.x + ua.x, 0.f));
          hv[1] = f2bf(fmaxf(va.y + ua.y, 0.f));
          hv[2] = f2bf(fmaxf(va.z + ua.z, 0.f));
          hv[3] = f2bf(fmaxf(va.w + ua.w, 0.f));
          hv[4] = f2bf(fmaxf(vb.x + ub.x, 0.f));
          hv[5] = f2bf(fmaxf(vb.y + ub.y, 0.f));
          hv[6] = f2bf(fmaxf(vb.z + ub.z, 0.f));
          hv[7] = f2bf(fmaxf(vb.w + ub.w, 0.f));
          int col16 = ks4 * 4 + w;
          int byteoff = cj * 256 + ((col16 * 16) ^ ((cj & 7) << 4));
          *reinterpret_cast<ushort8*>(hA + byteoff) = hv;
        }
      }
      __syncthreads();
      // ---- MFMA over this chunk ----
      #pragma unroll
      for (int mt = 0; mt < 4; ++mt) {
        int j = mt * 16 + (lane & 15);
        #pragma unroll
        for (int ksl = 0; ksl < 4; ++ksl) {
          int col16 = ksl * 4 + (lane >> 4);
          int byteoff = j * 256 + ((col16 * 16) ^ ((j & 7) << 4));
          short8v a = *reinterpret_cast<const short8v*>(hA + byteoff);
          acc[mt] = __builtin_amdgcn_mfma_f32_16x16x32_bf16(
              a, bfrag[ch * 4 + ksl], acc[mt], 0, 0, 0);
        }
      }
    }
    // ---- epilogue: store logits for this i ----
    if (cls < NCLS) {
      #pragma unroll
      for (int mt = 0; mt < 4; ++mt) {
        #pragma unroll
        for (int r = 0; r < 4; ++r) {
          int j = j0 + mt * 16 + ((lane >> 4) * 4) + r;
          if (j != i) {
            int p = i * (NN - 1) + (j > i ? j - 1 : j);
            out[2 * (size_t)NPAIR + (size_t)p * NCLS + cls] = acc[mt][r] + b2v;
          }
        }
      }
    }
  }
}

// --------------------------------------------------------------------------
extern "C" void kernel_launch(void* const* d_in, const int* in_sizes, int n_in,
                              void* d_out, int out_size, void* d_ws, size_t ws_size,
                              hipStream_t stream) {
  const float* node   = (const float*)d_in[0];
  const float* boxes  = (const float*)d_in[1];
  const float* w_in   = (const float*)d_in[2];
  const float* b_in   = (const float*)d_in[3];
  const float* w_out  = (const float*)d_in[4];
  const float* b_out  = (const float*)d_in[5];
  const float* fw1    = (const float*)d_in[6];
  const float* fb1    = (const float*)d_in[7];
  const float* fw2    = (const float*)d_in[8];
  const float* fb2    = (const float*)d_in[9];
  const float* ln1g   = (const float*)d_in[10];
  const float* ln1b   = (const float*)d_in[11];
  const float* ln2g   = (const float*)d_in[12];
  const float* ln2b   = (const float*)d_in[13];
  const float* mw1    = (const float*)d_in[14];
  const float* mb1    = (const float*)d_in[15];
  const float* mw2    = (const float*)d_in[16];
  const float* mb2    = (const float*)d_in[17];
  float* out = (float*)d_out;

  float* ws = (float*)d_ws;
  float* xbuf  = ws;                   // 384*256
  float* qkv   = xbuf  + 98304;        // 384*768
  float* sc    = qkv   + 294912;       // 4*384*384
  float* attno = sc    + 589824;       // 384*256
  float* proj  = attno + 98304;        // 384*256
  float* ffh   = proj  + 98304;        // 384*1024
  float* U     = ffh   + 393216;       // 384*512
  float* V     = U     + 196608;       // 384*512  (contiguous after U)
  unsigned short* w2frag = (unsigned short*)(V + 196608);  // 64KB
  float* kt    = (float*)(w2frag + 32768);                 // 4*64*384

  hipMemcpyAsync(xbuf, node, (size_t)NN * DM * sizeof(float),
                 hipMemcpyDeviceToDevice, stream);
  // independent of encoder:
  prep_w2frag<<<dim3(16), 256, 0, stream>>>(mw2, w2frag);
  pair_idx_kernel<<<dim3((NPAIR + 255) / 256), 256, 0, stream>>>(out);

  for (int l = 0; l < 2; ++l) {
    const float* wi  = w_in  + (size_t)l * DM * 768;
    const float* bi  = b_in  + (size_t)l * 768;
    const float* wo  = w_out + (size_t)l * DM * DM;
    const float* bo  = b_out + (size_t)l * DM;
    const float* w1l = fw1   + (size_t)l * DM * FF;
    const float* b1l = fb1   + (size_t)l * FF;
    const float* w2l = fw2   + (size_t)l * FF * DM;
    const float* b2l = fb2   + (size_t)l * DM;

    gemm_tile<<<dim3(12, 6, 1), 256, 0, stream>>>(xbuf, DM, 0, wi, 768, 0, bi,
                                                  qkv, 768, 0, DM, 1.f, 0);
    transpose_k<<<dim3(384), 256, 0, stream>>>(qkv, kt);
    gemm_tile<<<dim3(6, 6, NH), 256, 0, stream>>>(qkv, 768, 64, kt, NN, 64 * NN,
                                                  nullptr, sc, NN, (long)NN * NN,
                                                  64, 0.125f, 0);
    softmax_rows<<<dim3(NH * NN), 128, 0, stream>>>(sc);
    gemm_tile<<<dim3(1, 6, NH), 256, 0, stream>>>(sc, NN, (long)NN * NN,
                                                  qkv + 512, 768, 64, nullptr,
                                                  attno, DM, 64, NN, 1.f, 0);
    gemm_tile<<<dim3(4, 6, 1), 256, 0, stream>>>(attno, DM, 0, wo, DM, 0, bo,
                                                 proj, DM, 0, DM, 1.f, 0);
    add_ln<<<dim3(NN), 256, 0, stream>>>(xbuf, proj, ln1g + (size_t)l * DM, ln1b + (size_t)l * DM);
    gemm_tile<<<dim3(16, 6, 1), 256, 0, stream>>>(xbuf, DM, 0, w1l, FF, 0, b1l,
                                                  ffh, FF, 0, DM, 1.f, 1);
    gemm_tile<<<dim3(4, 6, 1), 256, 0, stream>>>(ffh, FF, 0, w2l, DM, 0, b2l,
                                                 proj, DM, 0, FF, 1.f, 0);
    add_ln<<<dim3(NN), 256, 0, stream>>>(xbuf, proj, ln2g + (size_t)l * DM, ln2b + (size_t)l * DM);
  }

  // relation MLP: U = x@W1[0:256]+b1, V = x@W1[256:512], + box terms
  gemm_tile<<<dim3(8, 6, 1), 256, 0, stream>>>(xbuf, DM, 0, mw1, HIDN, 0, mb1,
                                               U, HIDN, 0, DM, 1.f, 0);
  gemm_tile<<<dim3(8, 6, 1), 256, 0, stream>>>(xbuf, DM, 0, mw1 + (size_t)DM * HIDN,
                                               HIDN, 0, nullptr, V, HIDN, 0, DM, 1.f, 0);
  uv_fixup<<<dim3(NN * HIDN / 256), 256, 0, stream>>>(boxes, mw1, U, V);
  // pair GEMM on matrix cores
  pair_mfma<<<dim3(6, 96), 256, 0, stream>>>(U, V, w2frag, mb2, out);
}

// Round 4
// 329.360 us; speedup vs baseline: 3.5376x; 1.1352x over previous
//
#include <hip/hip_runtime.h>

#define NN 384
#define DM 256
#define NH 4
#define FF 1024
#define HIDN 512
#define NCLS 56
#define NPAIR (NN*(NN-1))   // 147072

typedef __attribute__((ext_vector_type(8))) short short8v;
typedef __attribute__((ext_vector_type(4))) float f32x4;
typedef __attribute__((ext_vector_type(8))) unsigned short ushort8;
typedef __attribute__((ext_vector_type(4))) unsigned int uint4v;

static __device__ __forceinline__ unsigned short f2bf(float f) {
  unsigned u = __float_as_uint(f);
  unsigned r = u + 0x7fff + ((u >> 16) & 1);   // RNE
  return (unsigned short)(r >> 16);
}
static __device__ __forceinline__ float bf2f(unsigned short v) {
  return __uint_as_float(((unsigned)v) << 16);
}
static __device__ __forceinline__ unsigned cvt_pk_bf16(float lo, float hi) {
  unsigned r;
  asm("v_cvt_pk_bf16_f32 %0, %1, %2" : "=v"(r) : "v"(lo), "v"(hi));
  return r;
}

// ---------------- tiled f32 GEMM 64x64: C = alpha*(A@B) + bias, opt relu ---
__global__ __launch_bounds__(256)
void gemm_tile(const float* __restrict__ A, int lda, long sA,
               const float* __restrict__ B, int ldb, long sB,
               const float* __restrict__ bias,
               float* __restrict__ C, int ldc, long sC,
               int K, float alpha, int relu) {
  __shared__ float As[16][64];
  __shared__ float Bs[16][64];
  A += (size_t)blockIdx.z * sA;
  B += (size_t)blockIdx.z * sB;
  C += (size_t)blockIdx.z * sC;
  int tid = threadIdx.x;
  int tx = tid & 15;
  int ty = tid >> 4;
  int m0 = blockIdx.y * 64;
  int n0 = blockIdx.x * 64;
  int la_r = tid >> 2;
  int la_k = (tid & 3) * 4;
  int lb_k = tid >> 4;
  int lb_n = (tid & 15) * 4;

  float acc[4][4] = {};
  float4 av = *reinterpret_cast<const float4*>(A + (size_t)(m0 + la_r) * lda + la_k);
  float4 bv = *reinterpret_cast<const float4*>(B + (size_t)lb_k * ldb + n0 + lb_n);
  int nchunk = K >> 4;
  for (int ch = 0; ch < nchunk; ++ch) {
    __syncthreads();
    As[la_k + 0][la_r] = av.x;
    As[la_k + 1][la_r] = av.y;
    As[la_k + 2][la_r] = av.z;
    As[la_k + 3][la_r] = av.w;
    *reinterpret_cast<float4*>(&Bs[lb_k][lb_n]) = bv;
    if (ch + 1 < nchunk) {
      int k0 = (ch + 1) << 4;
      av = *reinterpret_cast<const float4*>(A + (size_t)(m0 + la_r) * lda + k0 + la_k);
      bv = *reinterpret_cast<const float4*>(B + (size_t)(k0 + lb_k) * ldb + n0 + lb_n);
    }
    __syncthreads();
    #pragma unroll
    for (int k = 0; k < 16; ++k) {
      float4 a4 = *reinterpret_cast<const float4*>(&As[k][ty * 4]);
      float4 b4 = *reinterpret_cast<const float4*>(&Bs[k][tx * 4]);
      acc[0][0] += a4.x * b4.x; acc[0][1] += a4.x * b4.y; acc[0][2] += a4.x * b4.z; acc[0][3] += a4.x * b4.w;
      acc[1][0] += a4.y * b4.x; acc[1][1] += a4.y * b4.y; acc[1][2] += a4.y * b4.z; acc[1][3] += a4.y * b4.w;
      acc[2][0] += a4.z * b4.x; acc[2][1] += a4.z * b4.y; acc[2][2] += a4.z * b4.z; acc[2][3] += a4.z * b4.w;
      acc[3][0] += a4.w * b4.x; acc[3][1] += a4.w * b4.y; acc[3][2] += a4.w * b4.z; acc[3][3] += a4.w * b4.w;
    }
  }
  float4 bb = make_float4(0.f, 0.f, 0.f, 0.f);
  if (bias) bb = *reinterpret_cast<const float4*>(bias + n0 + tx * 4);
  #pragma unroll
  for (int i = 0; i < 4; ++i) {
    float4 r;
    r.x = acc[i][0] * alpha + bb.x;
    r.y = acc[i][1] * alpha + bb.y;
    r.z = acc[i][2] * alpha + bb.z;
    r.w = acc[i][3] * alpha + bb.w;
    if (relu) {
      r.x = fmaxf(r.x, 0.f); r.y = fmaxf(r.y, 0.f);
      r.z = fmaxf(r.z, 0.f); r.w = fmaxf(r.w, 0.f);
    }
    *reinterpret_cast<float4*>(C + (size_t)(m0 + ty * 4 + i) * ldc + n0 + tx * 4) = r;
  }
}

// ---------------- tiled f32 GEMM 32x32 (more blocks for small outputs) ----
__global__ __launch_bounds__(256)
void gemm32(const float* __restrict__ A, int lda, long sA,
            const float* __restrict__ B, int ldb, long sB,
            const float* __restrict__ bias,
            float* __restrict__ C, int ldc, long sC,
            int K, float alpha, int relu) {
  __shared__ float As[16][33];
  __shared__ float Bs[16][33];
  A += (size_t)blockIdx.z * sA;
  B += (size_t)blockIdx.z * sB;
  C += (size_t)blockIdx.z * sC;
  int tid = threadIdx.x;
  int tx = tid & 15;
  int ty = tid >> 4;
  int m0 = blockIdx.y * 32;
  int n0 = blockIdx.x * 32;
  float acc[2][2] = {};
  // stage assignments
  int ar = (tid & 127) >> 2;          // 0..31
  int ak = (tid & 3) * 4;             // 0,4,8,12
  int bk = (tid & 127) >> 3;          // 0..15
  int bn = ((tid & 127) & 7) * 4;     // 0..28
  bool doA = tid < 128;
  float4 pre;
  if (doA) pre = *reinterpret_cast<const float4*>(A + (size_t)(m0 + ar) * lda + ak);
  else     pre = *reinterpret_cast<const float4*>(B + (size_t)bk * ldb + n0 + bn);
  int nchunk = K >> 4;
  for (int ch = 0; ch < nchunk; ++ch) {
    __syncthreads();
    if (doA) {
      As[ak + 0][ar] = pre.x; As[ak + 1][ar] = pre.y;
      As[ak + 2][ar] = pre.z; As[ak + 3][ar] = pre.w;
    } else {
      Bs[bk][bn + 0] = pre.x; Bs[bk][bn + 1] = pre.y;
      Bs[bk][bn + 2] = pre.z; Bs[bk][bn + 3] = pre.w;
    }
    if (ch + 1 < nchunk) {
      int k0 = (ch + 1) << 4;
      if (doA) pre = *reinterpret_cast<const float4*>(A + (size_t)(m0 + ar) * lda + k0 + ak);
      else     pre = *reinterpret_cast<const float4*>(B + (size_t)(k0 + bk) * ldb + n0 + bn);
    }
    __syncthreads();
    #pragma unroll
    for (int k = 0; k < 16; ++k) {
      float a0 = As[k][ty * 2], a1 = As[k][ty * 2 + 1];
      float b0 = Bs[k][tx * 2], b1 = Bs[k][tx * 2 + 1];
      acc[0][0] += a0 * b0; acc[0][1] += a0 * b1;
      acc[1][0] += a1 * b0; acc[1][1] += a1 * b1;
    }
  }
  float bb0 = 0.f, bb1 = 0.f;
  if (bias) { bb0 = bias[n0 + tx * 2]; bb1 = bias[n0 + tx * 2 + 1]; }
  #pragma unroll
  for (int r = 0; r < 2; ++r) {
    float v0 = acc[r][0] * alpha + bb0;
    float v1 = acc[r][1] * alpha + bb1;
    if (relu) { v0 = fmaxf(v0, 0.f); v1 = fmaxf(v1, 0.f); }
    float2 st = make_float2(v0, v1);
    *reinterpret_cast<float2*>(C + (size_t)(m0 + ty * 2 + r) * ldc + n0 + tx * 2) = st;
  }
}

// ---------------- transpose K heads ---------------------------------------
__global__ __launch_bounds__(256)
void transpose_k(const float* __restrict__ qkv, float* __restrict__ kt) {
  int idx = blockIdx.x * 256 + threadIdx.x;
  int m = idx % NN;
  int d = (idx / NN) & 63;
  int h = idx / (NN * 64);
  kt[idx] = qkv[(size_t)m * 768 + 256 + h * 64 + d];
}

// ---------------- row softmax over 384 ------------------------------------
__global__ __launch_bounds__(128)
void softmax_rows(float* __restrict__ sc) {
  float* row = sc + (size_t)blockIdx.x * NN;
  int t = threadIdx.x;
  float v0 = row[t], v1 = row[t + 128], v2 = row[t + 256];
  __shared__ float red[128];
  float m = fmaxf(v0, fmaxf(v1, v2));
  red[t] = m; __syncthreads();
  for (int s = 64; s > 0; s >>= 1) { if (t < s) red[t] = fmaxf(red[t], red[t + s]); __syncthreads(); }
  m = red[0]; __syncthreads();
  float e0 = expf(v0 - m), e1 = expf(v1 - m), e2 = expf(v2 - m);
  red[t] = e0 + e1 + e2; __syncthreads();
  for (int s = 64; s > 0; s >>= 1) { if (t < s) red[t] += red[t + s]; __syncthreads(); }
  float inv = 1.0f / red[0];
  row[t] = e0 * inv; row[t + 128] = e1 * inv; row[t + 256] = e2 * inv;
}

// ---------------- residual add + LayerNorm --------------------------------
__global__ __launch_bounds__(256)
void add_ln(float* __restrict__ x, const float* __restrict__ r,
            const float* __restrict__ g, const float* __restrict__ b) {
  int i = blockIdx.x, t = threadIdx.x;
  float v = x[(size_t)i * DM + t] + r[(size_t)i * DM + t];
  __shared__ float red[256];
  red[t] = v; __syncthreads();
  for (int s = 128; s > 0; s >>= 1) { if (t < s) red[t] += red[t + s]; __syncthreads(); }
  float mu = red[0] * (1.0f / DM); __syncthreads();
  float dv = v - mu;
  red[t] = dv * dv; __syncthreads();
  for (int s = 128; s > 0; s >>= 1) { if (t < s) red[t] += red[t + s]; __syncthreads(); }
  float var = red[0] * (1.0f / DM);
  float inv = rsqrtf(var + 1e-5f);
  x[(size_t)i * DM + t] = dv * inv * g[t] + b[t];
}

// ------ add box terms; U stays f32, V goes to global bf16 -----------------
__global__ __launch_bounds__(256)
void uv_fixup(const float* __restrict__ boxes, const float* __restrict__ w1,
              float* __restrict__ U, const float* __restrict__ V,
              unsigned short* __restrict__ Vbf) {
  int idx = blockIdx.x * 256 + threadIdx.x;   // NN*HIDN
  int i = idx >> 9, k = idx & 511;
  float u = U[idx], v = V[idx];
  #pragma unroll
  for (int c = 0; c < 4; ++c) {
    float bv = boxes[i * 4 + c];
    u += bv * w1[(size_t)(512 + c) * HIDN + k];
    v += bv * w1[(size_t)(516 + c) * HIDN + k];
  }
  U[idx] = u;
  Vbf[idx] = f2bf(v);
}

// ---------------- pack W2 into MFMA B-fragment order (bf16) ---------------
__global__ __launch_bounds__(256)
void prep_w2frag(const float* __restrict__ w2, unsigned short* __restrict__ frag) {
  int idx = blockIdx.x * 256 + threadIdx.x;   // 16*4*64 = 4096
  int l = idx & 63;
  int nt = (idx >> 6) & 3;
  int ks = idx >> 8;
  int kb = ks * 32 + ((l >> 4) * 8);
  int n = nt * 16 + (l & 15);
  #pragma unroll
  for (int r = 0; r < 8; ++r) {
    float v = (n < NCLS) ? w2[(size_t)(kb + r) * NCLS + n] : 0.f;
    frag[(size_t)idx * 8 + r] = f2bf(v);
  }
}

// ---------------- pair indices output -------------------------------------
__global__ __launch_bounds__(256)
void pair_idx_kernel(float* __restrict__ out) {
  int p = blockIdx.x * 256 + threadIdx.x;
  if (p >= NPAIR) return;
  int i = p / (NN - 1);
  int r = p - i * (NN - 1);
  int j = r + (r >= i ? 1 : 0);
  out[2 * p + 0] = (float)i;
  out[2 * p + 1] = (float)j;
}

// ---------------- pair MLP via MFMA v2 ------------------------------------
// Block: 4 waves. j-tile 32 (2 M-tiles), i-tile 8. Wave = (mt, nt-pair).
// B-frags fully VGPR-resident (2 nt x 16 ks). hA[32][512] bf16 swizzled LDS.
__global__ __launch_bounds__(256, 2)
void pair_mfma(const float* __restrict__ U, const unsigned short* __restrict__ Vbf,
               const unsigned short* __restrict__ w2frag,
               const float* __restrict__ b2, float* __restrict__ out) {
  __shared__ char hA[32 * 1024];   // [32 j][512 k] bf16, XOR-swizzled
  int j0 = blockIdx.x * 32;
  int i0 = blockIdx.y * 8;
  int tid = threadIdx.x;
  int wave = tid >> 6;
  int lane = tid & 63;
  int mt = wave & 1;          // M-tile within j-tile
  int nth = wave >> 1;        // nt pair index: nts {2*nth, 2*nth+1}

  short8v bfrag0[16], bfrag1[16];
  #pragma unroll
  for (int ks = 0; ks < 16; ++ks) {
    bfrag0[ks] = *reinterpret_cast<const short8v*>(
        w2frag + ((size_t)(ks * 4 + nth * 2 + 0) * 64 + lane) * 8);
    bfrag1[ks] = *reinterpret_cast<const short8v*>(
        w2frag + ((size_t)(ks * 4 + nth * 2 + 1) * 64 + lane) * 8);
  }

  int colc = lane & 15;
  int cls0 = nth * 32 + colc;            // always < 56
  int cls1 = cls0 + 16;
  float b2v0 = b2[cls0];
  float b2v1 = (cls1 < NCLS) ? b2[cls1] : 0.f;

  // build assignment: row cj (0..31), k-segment kseg (64 cols)
  int cj = tid >> 3;
  int kseg = tid & 7;
  const ushort8* vrow = reinterpret_cast<const ushort8*>(
      Vbf + (size_t)(j0 + cj) * HIDN + kseg * 64);
  float* lg = out + 2 * (size_t)NPAIR;
  int arow = mt * 16 + colc;
  int agr = lane >> 4;

  for (int ii = 0; ii < 8; ++ii) {
    int i = i0 + ii;
    __syncthreads();   // previous MFMA reads done
    // ---- build hA rows for this i: h = relu(u + v) -> bf16 ----
    {
      const float4* u4 = reinterpret_cast<const float4*>(U + (size_t)i * HIDN + kseg * 64);
      #pragma unroll
      for (int s = 0; s < 8; ++s) {
        ushort8 v8 = vrow[s];
        float4 ua = u4[s * 2];
        float4 ub = u4[s * 2 + 1];
        float h0 = fmaxf(bf2f(v8[0]) + ua.x, 0.f);
        float h1 = fmaxf(bf2f(v8[1]) + ua.y, 0.f);
        float h2 = fmaxf(bf2f(v8[2]) + ua.z, 0.f);
        float h3 = fmaxf(bf2f(v8[3]) + ua.w, 0.f);
        float h4 = fmaxf(bf2f(v8[4]) + ub.x, 0.f);
        float h5 = fmaxf(bf2f(v8[5]) + ub.y, 0.f);
        float h6 = fmaxf(bf2f(v8[6]) + ub.z, 0.f);
        float h7 = fmaxf(bf2f(v8[7]) + ub.w, 0.f);
        uint4v pk;
        pk[0] = cvt_pk_bf16(h0, h1);
        pk[1] = cvt_pk_bf16(h2, h3);
        pk[2] = cvt_pk_bf16(h4, h5);
        pk[3] = cvt_pk_bf16(h6, h7);
        int gran = kseg * 8 + s;
        int byteoff = cj * 1024 + ((gran * 16) ^ ((cj & 7) << 4));
        *reinterpret_cast<uint4v*>(hA + byteoff) = pk;
      }
    }
    __syncthreads();
    // ---- MFMA: this wave's M-tile x 2 n-tiles over K=512 ----
    f32x4 acc0 = {}, acc1 = {};
    #pragma unroll
    for (int ks = 0; ks < 16; ++ks) {
      int gran = ks * 4 + agr;
      int byteoff = arow * 1024 + ((gran * 16) ^ ((arow & 7) << 4));
      short8v a = *reinterpret_cast<const short8v*>(hA + byteoff);
      acc0 = __builtin_amdgcn_mfma_f32_16x16x32_bf16(a, bfrag0[ks], acc0, 0, 0, 0);
      acc1 = __builtin_amdgcn_mfma_f32_16x16x32_bf16(a, bfrag1[ks], acc1, 0, 0, 0);
    }
    // ---- store logits ----
    #pragma unroll
    for (int r = 0; r < 4; ++r) {
      int j = j0 + mt * 16 + agr * 4 + r;
      if (j == i) continue;
      int p = i * (NN - 1) + (j > i ? j - 1 : j);
      lg[(size_t)p * NCLS + cls0] = acc0[r] + b2v0;
      if (cls1 < NCLS) lg[(size_t)p * NCLS + cls1] = acc1[r] + b2v1;
    }
  }
}

// --------------------------------------------------------------------------
extern "C" void kernel_launch(void* const* d_in, const int* in_sizes, int n_in,
                              void* d_out, int out_size, void* d_ws, size_t ws_size,
                              hipStream_t stream) {
  const float* node   = (const float*)d_in[0];
  const float* boxes  = (const float*)d_in[1];
  const float* w_in   = (const float*)d_in[2];
  const float* b_in   = (const float*)d_in[3];
  const float* w_out  = (const float*)d_in[4];
  const float* b_out  = (const float*)d_in[5];
  const float* fw1    = (const float*)d_in[6];
  const float* fb1    = (const float*)d_in[7];
  const float* fw2    = (const float*)d_in[8];
  const float* fb2    = (const float*)d_in[9];
  const float* ln1g   = (const float*)d_in[10];
  const float* ln1b   = (const float*)d_in[11];
  const float* ln2g   = (const float*)d_in[12];
  const float* ln2b   = (const float*)d_in[13];
  const float* mw1    = (const float*)d_in[14];
  const float* mb1    = (const float*)d_in[15];
  const float* mw2    = (const float*)d_in[16];
  const float* mb2    = (const float*)d_in[17];
  float* out = (float*)d_out;

  float* ws = (float*)d_ws;
  float* xbuf  = ws;                   // 384*256
  float* qkv   = xbuf  + 98304;        // 384*768
  float* sc    = qkv   + 294912;       // 4*384*384
  float* attno = sc    + 589824;       // 384*256
  float* proj  = attno + 98304;        // 384*256
  float* ffh   = proj  + 98304;        // 384*1024
  float* U     = ffh   + 393216;       // 384*512
  float* V     = U     + 196608;       // 384*512
  unsigned short* Vbf    = (unsigned short*)(V + 196608);    // 384*512 bf16
  unsigned short* w2frag = (unsigned short*)(V + 294912);    // 64KB
  float* kt    = V + 327680;                                 // 4*64*384

  hipMemcpyAsync(xbuf, node, (size_t)NN * DM * sizeof(float),
                 hipMemcpyDeviceToDevice, stream);
  prep_w2frag<<<dim3(16), 256, 0, stream>>>(mw2, w2frag);
  pair_idx_kernel<<<dim3((NPAIR + 255) / 256), 256, 0, stream>>>(out);

  for (int l = 0; l < 2; ++l) {
    const float* wi  = w_in  + (size_t)l * DM * 768;
    const float* bi  = b_in  + (size_t)l * 768;
    const float* wo  = w_out + (size_t)l * DM * DM;
    const float* bo  = b_out + (size_t)l * DM;
    const float* w1l = fw1   + (size_t)l * DM * FF;
    const float* b1l = fb1   + (size_t)l * FF;
    const float* w2l = fw2   + (size_t)l * FF * DM;
    const float* b2l = fb2   + (size_t)l * DM;

    gemm_tile<<<dim3(12, 6, 1), 256, 0, stream>>>(xbuf, DM, 0, wi, 768, 0, bi,
                                                  qkv, 768, 0, DM, 1.f, 0);
    transpose_k<<<dim3(384), 256, 0, stream>>>(qkv, kt);
    gemm_tile<<<dim3(6, 6, NH), 256, 0, stream>>>(qkv, 768, 64, kt, NN, 64 * NN,
                                                  nullptr, sc, NN, (long)NN * NN,
                                                  64, 0.125f, 0);
    softmax_rows<<<dim3(NH * NN), 128, 0, stream>>>(sc);
    // PV: per head [384,384]@[384,64] -> 32x32 tiles, 96 blocks
    gemm32<<<dim3(2, 12, NH), 256, 0, stream>>>(sc, NN, (long)NN * NN,
                                                qkv + 512, 768, 64, nullptr,
                                                attno, DM, 64, NN, 1.f, 0);
    // proj: [384,256]@[256,256] -> 96 blocks
    gemm32<<<dim3(8, 12, 1), 256, 0, stream>>>(attno, DM, 0, wo, DM, 0, bo,
                                               proj, DM, 0, DM, 1.f, 0);
    add_ln<<<dim3(NN), 256, 0, stream>>>(xbuf, proj, ln1g + (size_t)l * DM, ln1b + (size_t)l * DM);
    gemm_tile<<<dim3(16, 6, 1), 256, 0, stream>>>(xbuf, DM, 0, w1l, FF, 0, b1l,
                                                  ffh, FF, 0, DM, 1.f, 1);
    // ffn2: [384,1024]@[1024,256] -> 96 blocks
    gemm32<<<dim3(8, 12, 1), 256, 0, stream>>>(ffh, FF, 0, w2l, DM, 0, b2l,
                                               proj, DM, 0, FF, 1.f, 0);
    add_ln<<<dim3(NN), 256, 0, stream>>>(xbuf, proj, ln2g + (size_t)l * DM, ln2b + (size_t)l * DM);
  }

  // relation MLP: U = x@W1[0:256]+b1, V = x@W1[256:512], then box/bf16 fixup
  gemm_tile<<<dim3(8, 6, 1), 256, 0, stream>>>(xbuf, DM, 0, mw1, HIDN, 0, mb1,
                                               U, HIDN, 0, DM, 1.f, 0);
  gemm_tile<<<dim3(8, 6, 1), 256, 0, stream>>>(xbuf, DM, 0, mw1 + (size_t)DM * HIDN,
                                               HIDN, 0, nullptr, V, HIDN, 0, DM, 1.f, 0);
  uv_fixup<<<dim3(NN * HIDN / 256), 256, 0, stream>>>(boxes, mw1, U, V, Vbf);
  pair_mfma<<<dim3(12, 48), 256, 0, stream>>>(U, Vbf, w2frag, mb2, out);
}